// Round 6
// baseline (574.032 us; speedup 1.0000x reference)
//
#include <hip/hip_runtime.h>
#include <hip/hip_fp16.h>

#define BB 4
#define SS 2048
#define HH 16
#define DKK 64
#define DMODEL 1024

typedef __attribute__((ext_vector_type(8))) _Float16 half8;
typedef __attribute__((ext_vector_type(2))) __fp16 fp16x2;
typedef __attribute__((ext_vector_type(4))) __fp16 fp16x4;
typedef __attribute__((ext_vector_type(4))) float floatx4;

#define MFMA16(a, b, c) __builtin_amdgcn_mfma_f32_16x16x32_f16(a, b, c, 0, 0, 0)

// 8 * log2(e): reference scale is *8; softmax runs in exp2 domain
#define SCL2 11.5415603336f

// ---------------- async global->LDS, 16B per lane ------------------------------
__device__ __forceinline__ void gload_lds16(const _Float16* g, _Float16* l) {
    __builtin_amdgcn_global_load_lds(
        (const __attribute__((address_space(1))) void*)g,
        (__attribute__((address_space(3))) void*)l, 16, 0, 0);
}

// ---------------- fp32 -> fp16 convert of X body, k-unit XOR swizzle -----------
__device__ __forceinline__
void convert_x_body(const float* __restrict__ src, _Float16* __restrict__ dst,
                    int bidx)
{
    size_t base = ((size_t)bidx * 256 + threadIdx.x) * 8;
    int m = (int)(base >> 10);
    int kk = (int)(base & 1023);
    float4 a = *(const float4*)(src + base);
    float4 b = *(const float4*)(src + base + 4);
    half8 h;
    h[0] = (_Float16)a.x; h[1] = (_Float16)a.y; h[2] = (_Float16)a.z; h[3] = (_Float16)a.w;
    h[4] = (_Float16)b.x; h[5] = (_Float16)b.y; h[6] = (_Float16)b.z; h[7] = (_Float16)b.w;
    int kd = kk ^ ((m & 7) << 3);
    *(half8*)(dst + ((size_t)m << 10) + kd) = h;
}

// ---------------- W[k][n] -> WT[n][k] fp16 body, swizzle by (n&7) --------------
__device__ __forceinline__
void convert_wt_body(const float* __restrict__ W, _Float16* __restrict__ WT,
                     int bidx)
{
    __shared__ __attribute__((aligned(16))) _Float16 T[64][72];
    int kt = (bidx >> 4) << 6;
    int nt = (bidx & 15) << 6;
    int tid = threadIdx.x;
    #pragma unroll
    for (int p = 0; p < 4; p++) {
        int lin = tid + p * 256;
        int row = lin >> 4;
        int c4 = (lin & 15) << 2;
        float4 vv = *(const float4*)(W + (size_t)(kt + row) * DMODEL + nt + c4);
        T[c4 + 0][row] = (_Float16)vv.x;
        T[c4 + 1][row] = (_Float16)vv.y;
        T[c4 + 2][row] = (_Float16)vv.z;
        T[c4 + 3][row] = (_Float16)vv.w;
    }
    __syncthreads();
    #pragma unroll
    for (int p = 0; p < 2; p++) {
        int lin = tid + p * 256;
        int nl = lin >> 3;
        int u = lin & 7;
        half8 h = *(const half8*)&T[nl][u * 8];
        int n = nt + nl;
        int kd = kt + ((u ^ (n & 7)) << 3);
        *(half8*)(WT + (size_t)n * DMODEL + kd) = h;
    }
}

__global__ __launch_bounds__(256)
void convert_x(const float* __restrict__ q, const float* __restrict__ k,
               const float* __restrict__ v, _Float16* __restrict__ xq,
               _Float16* __restrict__ xk, _Float16* __restrict__ xv)
{
    int z = blockIdx.y;
    convert_x_body(z == 0 ? q : z == 1 ? k : v,
                   z == 0 ? xq : z == 1 ? xk : xv, blockIdx.x);
}

__global__ __launch_bounds__(256)
void convert_wt(const float* __restrict__ wq, const float* __restrict__ wk,
                const float* __restrict__ wv, _Float16* __restrict__ tq,
                _Float16* __restrict__ tk, _Float16* __restrict__ tv)
{
    int z = blockIdx.y;
    convert_wt_body(z == 0 ? wq : z == 1 ? wk : wv,
                    z == 0 ? tq : z == 1 ? tk : tv, blockIdx.x);
}

// fused converts: y=0..2 -> X converts; y=3 -> the 768 WT blocks
__global__ __launch_bounds__(256)
void convert_all(const float* __restrict__ q, const float* __restrict__ k,
                 const float* __restrict__ v, const float* __restrict__ wq,
                 const float* __restrict__ wk, const float* __restrict__ wv,
                 _Float16* __restrict__ xq, _Float16* __restrict__ xk,
                 _Float16* __restrict__ xv, _Float16* __restrict__ tq,
                 _Float16* __restrict__ tk, _Float16* __restrict__ tv)
{
    int y = blockIdx.y;
    if (y < 3) {
        convert_x_body(y == 0 ? q : y == 1 ? k : v,
                       y == 0 ? xq : y == 1 ? xk : xv, blockIdx.x);
    } else {
        if (blockIdx.x >= 768) return;
        int z = blockIdx.x >> 8;
        convert_wt_body(z == 0 ? wq : z == 1 ? wk : wv,
                        z == 0 ? tq : z == 1 ? tk : tv, blockIdx.x & 255);
    }
}

// ---------------- 128x128 projection GEMM body ---------------------------------
template <int VMODE>
__device__ __forceinline__
void proj_body(const _Float16* __restrict__ X, const _Float16* __restrict__ WT,
               const float* __restrict__ bias, _Float16* __restrict__ out,
               int bidx)
{
    __shared__ __attribute__((aligned(16))) _Float16 As[128 * 64];
    __shared__ __attribute__((aligned(16))) _Float16 Bs[128 * 64];
    const int tid = threadIdx.x;
    const int wave = tid >> 6, lane = tid & 63, quad = lane >> 4, l16 = lane & 15;
    const int wm = wave >> 1, wn = wave & 1;
    const int m0 = (bidx >> 3) << 7;
    const int n0 = (bidx & 7) << 7;
    const int lrow = lane >> 3;
    const int lcol = (lane & 7) << 3;

    floatx4 acc[4][4] = {};

    for (int k0 = 0; k0 < DMODEL; k0 += 64) {
        __syncthreads();
        #pragma unroll
        for (int c = 0; c < 4; c++) {
            int row = c * 32 + wave * 8;
            gload_lds16(X + (size_t)(m0 + row + lrow) * DMODEL + k0 + lcol,
                        As + (size_t)row * 64);
            gload_lds16(WT + (size_t)(n0 + row + lrow) * DMODEL + k0 + lcol,
                        Bs + (size_t)row * 64);
        }
        __syncthreads();
        #pragma unroll
        for (int ks = 0; ks < 2; ks++) {
            int ccol = ((ks * 4 + quad) ^ (l16 & 7)) << 3;
            half8 af[4], bf[4];
            #pragma unroll
            for (int i = 0; i < 4; i++)
                af[i] = *(const half8*)(As + (wm * 64 + i * 16 + l16) * 64 + ccol);
            #pragma unroll
            for (int j = 0; j < 4; j++)
                bf[j] = *(const half8*)(Bs + (wn * 64 + j * 16 + l16) * 64 + ccol);
            #pragma unroll
            for (int i = 0; i < 4; i++)
                #pragma unroll
                for (int j = 0; j < 4; j++)
                    acc[i][j] = VMODE ? MFMA16(bf[j], af[i], acc[i][j])
                                      : MFMA16(af[i], bf[j], acc[i][j]);
        }
    }

    if (VMODE == 0) {
        #pragma unroll
        for (int j = 0; j < 4; j++) {
            int ng = n0 + wn * 64 + j * 16 + l16;
            int h = ng >> 6, d = ng & 63;
            float bv = bias[ng];
            #pragma unroll
            for (int i = 0; i < 4; i++)
                #pragma unroll
                for (int r = 0; r < 4; r++) {
                    int mg = m0 + wm * 64 + i * 16 + quad * 4 + r;
                    int bb = mg >> 11, s = mg & 2047;
                    out[(((size_t)bb * HH + h) * SS + s) * DKK + d] =
                        (_Float16)(acc[i][j][r] + bv);
                }
        }
    } else {
        #pragma unroll
        for (int j = 0; j < 4; j++)
            #pragma unroll
            for (int r = 0; r < 4; r++) {
                int ng = n0 + wn * 64 + j * 16 + quad * 4 + r;
                int h = ng >> 6, d = ng & 63;
                float bv = bias[ng];
                #pragma unroll
                for (int i = 0; i < 4; i++) {
                    int mg = m0 + wm * 64 + i * 16 + l16;
                    int bb = mg >> 11, s = mg & 2047;
                    out[(((size_t)bb * HH + h) * DKK + d) * SS + s] =
                        (_Float16)(acc[i][j][r] + bv);
                }
            }
    }
}

template <int VMODE>
__global__ __launch_bounds__(256)
void proj128(const _Float16* __restrict__ X, const _Float16* __restrict__ WT,
             const float* __restrict__ bias, _Float16* __restrict__ out)
{
    proj_body<VMODE>(X, WT, bias, out, blockIdx.x);
}

// all three projections in one launch (requires non-aliased buffers)
__global__ __launch_bounds__(256)
void proj_all(const _Float16* __restrict__ Xq, const _Float16* __restrict__ Xk,
              const _Float16* __restrict__ Xv, const _Float16* __restrict__ WTq,
              const _Float16* __restrict__ WTk, const _Float16* __restrict__ WTv,
              const float* __restrict__ bq, const float* __restrict__ bk,
              const float* __restrict__ bv, _Float16* __restrict__ Qh,
              _Float16* __restrict__ Kh, _Float16* __restrict__ VTh)
{
    int z = blockIdx.y;
    if (z == 0)      proj_body<0>(Xq, WTq, bq, Qh, blockIdx.x);
    else if (z == 1) proj_body<0>(Xk, WTk, bk, Kh, blockIdx.x);
    else             proj_body<1>(Xv, WTv, bv, VTh, blockIdx.x);
}

// ---------------- flash attention v4 -------------------------------------------
// Transposed scores (S^T, O^T) as in v3, plus:
//  - K frags for tile t+1 loaded right after QK MFMAs issue (overlap softmax)
//  - V frags for tile t+1 loaded after PV MFMAs issue
//  - Plds mt-dim dropped (DS in-order per wave), P written as one b64
//  - explicit tree reductions; launch_bounds(256,4) pins 4 waves/SIMD
__global__ __launch_bounds__(256, 4)
void flash4(const _Float16* __restrict__ Qw, const _Float16* __restrict__ Kw,
            const _Float16* __restrict__ VTw, const int* __restrict__ mask,
            const float* __restrict__ resid, float* __restrict__ out)
{
    __shared__ float Bias[SS];                                         // 8 KB
    __shared__ __attribute__((aligned(16))) _Float16 Plds[4][16][72];  // 9 KB

    const int tid = threadIdx.x;
    const int wave = tid >> 6, lane = tid & 63, quad = lane >> 4, l16 = lane & 15;
    const int bx = blockIdx.x;
    const int xcd = bx & 7;
    const int jj = bx >> 3;
    const int bh = ((jj >> 4) << 3) | xcd;   // all 16 q-tiles of a bh on one XCD
    const int qt = jj & 15;
    const int b = bh >> 4;
    const int h = bh & 15;
    const int qbase = qt * 128 + wave * 32;

    // stage mask -> fp32 additive bias
    const int* mk = mask + b * SS;
    for (int i = tid; i < SS; i += 256)
        Bias[i] = mk[i] ? 0.f : -1.0e9f;
    __syncthreads();

    // Q B-frags: n=q=l16, k=dk
    half8 qf[2][2];
    #pragma unroll
    for (int mt = 0; mt < 2; mt++) {
        const _Float16* Qp = Qw + ((size_t)bh * SS + qbase + mt * 16 + l16) * DKK;
        qf[mt][0] = *(const half8*)(Qp + quad * 8);
        qf[mt][1] = *(const half8*)(Qp + 32 + quad * 8);
    }

    float mrow[2] = {-3.0e38f, -3.0e38f};
    float lrow[2] = {0.f, 0.f};
    floatx4 oacc[2][4] = {};   // O^T: [mt][dt]; col=l16=q, row=quad*4+r=d-local

    const _Float16* Kbase = Kw + (size_t)bh * SS * DKK;
    const _Float16* Vbase = VTw + (size_t)bh * DKK * SS;

    // preload tile 0 K/V frags
    half8 kf[2][4], vf[2][4];
    #pragma unroll
    for (int ks = 0; ks < 2; ks++)
        #pragma unroll
        for (int k2 = 0; k2 < 4; k2++)
            kf[ks][k2] = *(const half8*)(Kbase
                + (size_t)(k2 * 16 + l16) * DKK + ks * 32 + quad * 8);
    #pragma unroll
    for (int ks = 0; ks < 2; ks++)
        #pragma unroll
        for (int dt = 0; dt < 4; dt++)
            vf[ks][dt] = *(const half8*)(Vbase
                + (size_t)(dt * 16 + l16) * SS + ks * 32 + quad * 8);

    for (int kt = 0; kt < SS / 64; kt++) {
        const int kb = kt * 64;
        const int kbn = ((kt + 1) & 31) * 64;   // wraps: redundant last prefetch

        // bias for keys kb + k2*16 + quad*4 + r (LDS broadcast across l16)
        float4 bs[4];
        #pragma unroll
        for (int k2 = 0; k2 < 4; k2++)
            bs[k2] = *(const float4*)&Bias[kb + k2 * 16 + quad * 4];

        // S^T: D[m=key][n=q]
        floatx4 sacc[2][4] = {};
        #pragma unroll
        for (int mt = 0; mt < 2; mt++)
            #pragma unroll
            for (int ks = 0; ks < 2; ks++)
                #pragma unroll
                for (int k2 = 0; k2 < 4; k2++)
                    sacc[mt][k2] = MFMA16(kf[ks][k2], qf[mt][ks], sacc[mt][k2]);

        // prefetch next K tile (kf regs free after MFMA issue; overlaps softmax)
        #pragma unroll
        for (int ks = 0; ks < 2; ks++)
            #pragma unroll
            for (int k2 = 0; k2 < 4; k2++)
                kf[ks][k2] = *(const half8*)(Kbase
                    + (size_t)(kbn + k2 * 16 + l16) * DKK + ks * 32 + quad * 8);

        #pragma unroll
        for (int mt = 0; mt < 2; mt++) {
            float p[4][4];
            #pragma unroll
            for (int k2 = 0; k2 < 4; k2++) {
                const float* bp = (const float*)&bs[k2];
                #pragma unroll
                for (int r = 0; r < 4; r++)
                    p[k2][r] = fmaf(sacc[mt][k2][r], SCL2, bp[r]);
            }
            // tree max (4 levels) + 2 cross-quad shfls
            float mk2[4];
            #pragma unroll
            for (int k2 = 0; k2 < 4; k2++)
                mk2[k2] = fmaxf(fmaxf(p[k2][0], p[k2][1]),
                                fmaxf(p[k2][2], p[k2][3]));
            float t = fmaxf(fmaxf(mk2[0], mk2[1]), fmaxf(mk2[2], mk2[3]));
            t = fmaxf(t, __shfl_xor(t, 16, 64));
            t = fmaxf(t, __shfl_xor(t, 32, 64));
            float mn = fmaxf(mrow[mt], t);
            float al = exp2f(mrow[mt] - mn);
            mrow[mt] = mn;

            float sk2[4];
            #pragma unroll
            for (int k2 = 0; k2 < 4; k2++) {
                #pragma unroll
                for (int r = 0; r < 4; r++)
                    p[k2][r] = exp2f(p[k2][r] - mn);
                sk2[k2] = (p[k2][0] + p[k2][1]) + (p[k2][2] + p[k2][3]);
            }
            float ps = (sk2[0] + sk2[1]) + (sk2[2] + sk2[3]);
            ps += __shfl_xor(ps, 16, 64);
            ps += __shfl_xor(ps, 32, 64);
            lrow[mt] = lrow[mt] * al + ps;

            // P store: 4 contiguous halves -> single b64 per k2
            #pragma unroll
            for (int k2 = 0; k2 < 4; k2++) {
                fp16x2 pa = __builtin_amdgcn_cvt_pkrtz(p[k2][0], p[k2][1]);
                fp16x2 pb = __builtin_amdgcn_cvt_pkrtz(p[k2][2], p[k2][3]);
                fp16x4 w = __builtin_shufflevector(pa, pb, 0, 1, 2, 3);
                *(fp16x4*)&Plds[wave][l16][k2 * 16 + quad * 4] = w;
            }
            // alpha rescale (lane-uniform al)
            #pragma unroll
            for (int dt = 0; dt < 4; dt++)
                oacc[mt][dt] *= al;

            // PV: O^T += V^T x P^T  (DS in-order per wave: mt1 writes can't
            // pass mt0 reads on the same addresses)
            #pragma unroll
            for (int ks = 0; ks < 2; ks++) {
                half8 pf = *(const half8*)&Plds[wave][l16][ks * 32 + quad * 8];
                #pragma unroll
                for (int dt = 0; dt < 4; dt++)
                    oacc[mt][dt] = MFMA16(vf[ks][dt], pf, oacc[mt][dt]);
            }
        }

        // prefetch next V tile (vf regs free after PV issue; overlaps next QK)
        #pragma unroll
        for (int ks = 0; ks < 2; ks++)
            #pragma unroll
            for (int dt = 0; dt < 4; dt++)
                vf[ks][dt] = *(const half8*)(Vbase
                    + (size_t)(dt * 16 + l16) * SS + kbn + ks * 32 + quad * 8);
    }

    // epilogue: float4 loads/stores; rl lane-uniform
    #pragma unroll
    for (int mt = 0; mt < 2; mt++) {
        float rl = 1.0f / lrow[mt];
        int s = qbase + mt * 16 + l16;
        size_t rowoff = ((size_t)b * SS + s) * DMODEL + h * DKK;
        #pragma unroll
        for (int dt = 0; dt < 4; dt++) {
            size_t gi = rowoff + dt * 16 + quad * 4;
            float4 rv = *(const float4*)&resid[gi];
            float4 ov;
            ov.x = oacc[mt][dt][0] * rl + rv.x;
            ov.y = oacc[mt][dt][1] * rl + rv.y;
            ov.z = oacc[mt][dt][2] * rl + rv.z;
            ov.w = oacc[mt][dt][3] * rl + rv.w;
            *(float4*)&out[gi] = ov;
        }
    }
}

// ---------------------------------------------------------------------------
extern "C" void kernel_launch(void* const* d_in, const int* in_sizes, int n_in,
                              void* d_out, int out_size, void* d_ws, size_t ws_size,
                              hipStream_t stream)
{
    const float* q    = (const float*)d_in[0];
    const float* k    = (const float*)d_in[1];
    const float* v    = (const float*)d_in[2];
    const int*   mask = (const int*)d_in[3];
    const float* wq   = (const float*)d_in[4];
    const float* bq   = (const float*)d_in[5];
    const float* wk   = (const float*)d_in[6];
    const float* bk   = (const float*)d_in[7];
    const float* wv   = (const float*)d_in[8];
    const float* bv   = (const float*)d_in[9];
    float* out = (float*)d_out;

    const size_t TENS = (size_t)BB * SS * HH * DKK;   // 8388608 halves
    const size_t WSZ  = (size_t)DMODEL * DMODEL;      // 1048576 halves
    _Float16* base = (_Float16*)d_ws;

    bool big = ws_size >= (6 * TENS + 3 * WSZ) * sizeof(_Float16);
    _Float16 *Xq, *Xk, *Xv, *Qh, *Kh, *VTh, *WTq;
    if (big) {
        Xq = base;            Xk = base + TENS;     Xv = base + 2 * TENS;
        Qh = base + 3 * TENS; Kh = base + 4 * TENS; VTh = base + 5 * TENS;
        WTq = base + 6 * TENS;
    } else {
        // stream-ordered aliasing: Kh reuses Xq's slot, VTh reuses Xk's slot
        Xq = base;            Xk = base + TENS;     Xv = base + 2 * TENS;
        Qh = base + 3 * TENS; Kh = Xq;              VTh = Xk;
        WTq = base + 4 * TENS;
    }
    _Float16* WTk = WTq + WSZ;
    _Float16* WTv = WTk + WSZ;

    if (big) {
        hipLaunchKernelGGL(convert_all, dim3(4096, 4), dim3(256), 0, stream,
                           q, k, v, wq, wk, wv, Xq, Xk, Xv, WTq, WTk, WTv);
        hipLaunchKernelGGL(proj_all, dim3(512, 3), dim3(256), 0, stream,
                           Xq, Xk, Xv, WTq, WTk, WTv, bq, bk, bv, Qh, Kh, VTh);
    } else {
        hipLaunchKernelGGL(convert_x, dim3(4096, 3), dim3(256), 0, stream,
                           q, k, v, Xq, Xk, Xv);
        hipLaunchKernelGGL(convert_wt, dim3(256, 3), dim3(256), 0, stream,
                           wq, wk, wv, WTq, WTk, WTv);
        hipLaunchKernelGGL((proj128<0>), dim3(512), dim3(256), 0, stream, Xq, WTq, bq, Qh);
        hipLaunchKernelGGL((proj128<0>), dim3(512), dim3(256), 0, stream, Xk, WTk, bk, Kh);
        hipLaunchKernelGGL((proj128<1>), dim3(512), dim3(256), 0, stream, Xv, WTv, bv, VTh);
    }
    hipLaunchKernelGGL(flash4, dim3(BB * HH * (SS / 128)), dim3(256), 0, stream,
                       Qh, Kh, VTh, mask, q, out);
}

// Round 7
// 460.345 us; speedup vs baseline: 1.2470x; 1.2470x over previous
//
#include <hip/hip_runtime.h>
#include <hip/hip_fp16.h>

#define BB 4
#define SS 2048
#define HH 16
#define DKK 64
#define DMODEL 1024

typedef __attribute__((ext_vector_type(8))) _Float16 half8;
typedef __attribute__((ext_vector_type(2))) __fp16 fp16x2;
typedef __attribute__((ext_vector_type(4))) float floatx4;

#define MFMA16(a, b, c) __builtin_amdgcn_mfma_f32_16x16x32_f16(a, b, c, 0, 0, 0)

// 8 * log2(e): reference scale is *8; softmax runs in exp2 domain
#define SCL2 11.5415603336f

// ---------------- async global->LDS, 16B per lane ------------------------------
__device__ __forceinline__ void gload_lds16(const _Float16* g, _Float16* l) {
    __builtin_amdgcn_global_load_lds(
        (const __attribute__((address_space(1))) void*)g,
        (__attribute__((address_space(3))) void*)l, 16, 0, 0);
}

// ---------------- fp32 -> fp16 convert of X body, k-unit XOR swizzle -----------
__device__ __forceinline__
void convert_x_body(const float* __restrict__ src, _Float16* __restrict__ dst,
                    int bidx)
{
    size_t base = ((size_t)bidx * 256 + threadIdx.x) * 8;
    int m = (int)(base >> 10);
    int kk = (int)(base & 1023);
    float4 a = *(const float4*)(src + base);
    float4 b = *(const float4*)(src + base + 4);
    half8 h;
    h[0] = (_Float16)a.x; h[1] = (_Float16)a.y; h[2] = (_Float16)a.z; h[3] = (_Float16)a.w;
    h[4] = (_Float16)b.x; h[5] = (_Float16)b.y; h[6] = (_Float16)b.z; h[7] = (_Float16)b.w;
    int kd = kk ^ ((m & 7) << 3);
    *(half8*)(dst + ((size_t)m << 10) + kd) = h;
}

// ---------------- W[k][n] -> WT[n][k] fp16 body, swizzle by (n&7) --------------
__device__ __forceinline__
void convert_wt_body(const float* __restrict__ W, _Float16* __restrict__ WT,
                     int bidx)
{
    __shared__ __attribute__((aligned(16))) _Float16 T[64][72];
    int kt = (bidx >> 4) << 6;
    int nt = (bidx & 15) << 6;
    int tid = threadIdx.x;
    #pragma unroll
    for (int p = 0; p < 4; p++) {
        int lin = tid + p * 256;
        int row = lin >> 4;
        int c4 = (lin & 15) << 2;
        float4 vv = *(const float4*)(W + (size_t)(kt + row) * DMODEL + nt + c4);
        T[c4 + 0][row] = (_Float16)vv.x;
        T[c4 + 1][row] = (_Float16)vv.y;
        T[c4 + 2][row] = (_Float16)vv.z;
        T[c4 + 3][row] = (_Float16)vv.w;
    }
    __syncthreads();
    #pragma unroll
    for (int p = 0; p < 2; p++) {
        int lin = tid + p * 256;
        int nl = lin >> 3;
        int u = lin & 7;
        half8 h = *(const half8*)&T[nl][u * 8];
        int n = nt + nl;
        int kd = kt + ((u ^ (n & 7)) << 3);
        *(half8*)(WT + (size_t)n * DMODEL + kd) = h;
    }
}

__global__ __launch_bounds__(256)
void convert_x(const float* __restrict__ q, const float* __restrict__ k,
               const float* __restrict__ v, _Float16* __restrict__ xq,
               _Float16* __restrict__ xk, _Float16* __restrict__ xv)
{
    int z = blockIdx.y;
    convert_x_body(z == 0 ? q : z == 1 ? k : v,
                   z == 0 ? xq : z == 1 ? xk : xv, blockIdx.x);
}

__global__ __launch_bounds__(256)
void convert_wt(const float* __restrict__ wq, const float* __restrict__ wk,
                const float* __restrict__ wv, _Float16* __restrict__ tq,
                _Float16* __restrict__ tk, _Float16* __restrict__ tv)
{
    int z = blockIdx.y;
    convert_wt_body(z == 0 ? wq : z == 1 ? wk : wv,
                    z == 0 ? tq : z == 1 ? tk : tv, blockIdx.x);
}

// fused converts: y=0..2 -> X converts; y=3 -> the 768 WT blocks
__global__ __launch_bounds__(256)
void convert_all(const float* __restrict__ q, const float* __restrict__ k,
                 const float* __restrict__ v, const float* __restrict__ wq,
                 const float* __restrict__ wk, const float* __restrict__ wv,
                 _Float16* __restrict__ xq, _Float16* __restrict__ xk,
                 _Float16* __restrict__ xv, _Float16* __restrict__ tq,
                 _Float16* __restrict__ tk, _Float16* __restrict__ tv)
{
    int y = blockIdx.y;
    if (y < 3) {
        convert_x_body(y == 0 ? q : y == 1 ? k : v,
                       y == 0 ? xq : y == 1 ? xk : xv, blockIdx.x);
    } else {
        if (blockIdx.x >= 768) return;
        int z = blockIdx.x >> 8;
        convert_wt_body(z == 0 ? wq : z == 1 ? wk : wv,
                        z == 0 ? tq : z == 1 ? tk : tv, blockIdx.x & 255);
    }
}

// ---------------- 128x128 projection GEMM body ---------------------------------
// XCD-aware tile map: the 8 n-blocks sharing one X m-tile all get the same
// bidx%8 -> same XCD (dispatch round-robins XCD by linear block id), so the
// 256KB X tile is fetched once per XCD instead of 8 times.
template <int VMODE>
__device__ __forceinline__
void proj_body(const _Float16* __restrict__ X, const _Float16* __restrict__ WT,
               const float* __restrict__ bias, _Float16* __restrict__ out,
               int bidx)
{
    __shared__ __attribute__((aligned(16))) _Float16 As[128 * 64];
    __shared__ __attribute__((aligned(16))) _Float16 Bs[128 * 64];
    const int tid = threadIdx.x;
    const int wave = tid >> 6, lane = tid & 63, quad = lane >> 4, l16 = lane & 15;
    const int wm = wave >> 1, wn = wave & 1;
    const int m0 = ((bidx & 7) | ((bidx >> 6) << 3)) << 7;  // m-block = bidx%8 + 8*(bidx/64)
    const int n0 = ((bidx >> 3) & 7) << 7;                  // n-block = (bidx/8)%8
    const int lrow = lane >> 3;
    const int lcol = (lane & 7) << 3;

    floatx4 acc[4][4] = {};

    for (int k0 = 0; k0 < DMODEL; k0 += 64) {
        __syncthreads();
        #pragma unroll
        for (int c = 0; c < 4; c++) {
            int row = c * 32 + wave * 8;
            gload_lds16(X + (size_t)(m0 + row + lrow) * DMODEL + k0 + lcol,
                        As + (size_t)row * 64);
            gload_lds16(WT + (size_t)(n0 + row + lrow) * DMODEL + k0 + lcol,
                        Bs + (size_t)row * 64);
        }
        __syncthreads();
        #pragma unroll
        for (int ks = 0; ks < 2; ks++) {
            int ccol = ((ks * 4 + quad) ^ (l16 & 7)) << 3;
            half8 af[4], bf[4];
            #pragma unroll
            for (int i = 0; i < 4; i++)
                af[i] = *(const half8*)(As + (wm * 64 + i * 16 + l16) * 64 + ccol);
            #pragma unroll
            for (int j = 0; j < 4; j++)
                bf[j] = *(const half8*)(Bs + (wn * 64 + j * 16 + l16) * 64 + ccol);
            #pragma unroll
            for (int i = 0; i < 4; i++)
                #pragma unroll
                for (int j = 0; j < 4; j++)
                    acc[i][j] = VMODE ? MFMA16(bf[j], af[i], acc[i][j])
                                      : MFMA16(af[i], bf[j], acc[i][j]);
        }
    }

    if (VMODE == 0) {
        #pragma unroll
        for (int j = 0; j < 4; j++) {
            int ng = n0 + wn * 64 + j * 16 + l16;
            int h = ng >> 6, d = ng & 63;
            float bv = bias[ng];
            #pragma unroll
            for (int i = 0; i < 4; i++)
                #pragma unroll
                for (int r = 0; r < 4; r++) {
                    int mg = m0 + wm * 64 + i * 16 + quad * 4 + r;
                    int bb = mg >> 11, s = mg & 2047;
                    out[(((size_t)bb * HH + h) * SS + s) * DKK + d] =
                        (_Float16)(acc[i][j][r] + bv);
                }
        }
    } else {
        #pragma unroll
        for (int j = 0; j < 4; j++)
            #pragma unroll
            for (int r = 0; r < 4; r++) {
                int ng = n0 + wn * 64 + j * 16 + quad * 4 + r;
                int h = ng >> 6, d = ng & 63;
                float bv = bias[ng];
                #pragma unroll
                for (int i = 0; i < 4; i++) {
                    int mg = m0 + wm * 64 + i * 16 + l16;
                    int bb = mg >> 11, s = mg & 2047;
                    out[(((size_t)bb * HH + h) * DKK + d) * SS + s] =
                        (_Float16)(acc[i][j][r] + bv);
                }
            }
    }
}

template <int VMODE>
__global__ __launch_bounds__(256)
void proj128(const _Float16* __restrict__ X, const _Float16* __restrict__ WT,
             const float* __restrict__ bias, _Float16* __restrict__ out)
{
    proj_body<VMODE>(X, WT, bias, out, blockIdx.x);
}

// all three projections in one launch (requires non-aliased buffers)
__global__ __launch_bounds__(256)
void proj_all(const _Float16* __restrict__ Xq, const _Float16* __restrict__ Xk,
              const _Float16* __restrict__ Xv, const _Float16* __restrict__ WTq,
              const _Float16* __restrict__ WTk, const _Float16* __restrict__ WTv,
              const float* __restrict__ bq, const float* __restrict__ bk,
              const float* __restrict__ bv, _Float16* __restrict__ Qh,
              _Float16* __restrict__ Kh, _Float16* __restrict__ VTh)
{
    int z = blockIdx.y;
    if (z == 0)      proj_body<0>(Xq, WTq, bq, Qh, blockIdx.x);
    else if (z == 1) proj_body<0>(Xk, WTk, bk, Kh, blockIdx.x);
    else             proj_body<1>(Xv, WTv, bv, VTh, blockIdx.x);
}

// ---------------- flash attention v3 (R5 known-good): transposed scores --------
// S^T = MFMA(kf, qf): col=l16=q  -> per-row softmax state is one scalar/lane.
// O accumulated as O^T = MFMA(vf, pf); epilogue float4.
__global__ __launch_bounds__(256)
void flash3(const _Float16* __restrict__ Qw, const _Float16* __restrict__ Kw,
            const _Float16* __restrict__ VTw, const int* __restrict__ mask,
            const float* __restrict__ resid, float* __restrict__ out)
{
    __shared__ float Bias[SS];                                            // 8 KB
    __shared__ __attribute__((aligned(16))) _Float16 Plds[4][2][16][72];  // 18 KB

    const int tid = threadIdx.x;
    const int wave = tid >> 6, lane = tid & 63, quad = lane >> 4, l16 = lane & 15;
    const int bx = blockIdx.x;
    const int xcd = bx & 7;
    const int jj = bx >> 3;
    const int bh = ((jj >> 4) << 3) | xcd;   // all 16 q-tiles of a bh on one XCD
    const int qt = jj & 15;
    const int b = bh >> 4;
    const int h = bh & 15;
    const int qbase = qt * 128 + wave * 32;

    // stage mask -> fp32 additive bias (exp2 domain; -1e9 kills)
    const int* mk = mask + b * SS;
    for (int i = tid; i < SS; i += 256)
        Bias[i] = mk[i] ? 0.f : -1.0e9f;
    __syncthreads();

    // Q B-frags: n=q=l16, k=dk
    half8 qf[2][2];
    #pragma unroll
    for (int mt = 0; mt < 2; mt++) {
        const _Float16* Qp = Qw + ((size_t)bh * SS + qbase + mt * 16 + l16) * DKK;
        qf[mt][0] = *(const half8*)(Qp + quad * 8);
        qf[mt][1] = *(const half8*)(Qp + 32 + quad * 8);
    }

    float mrow[2] = {-3.0e38f, -3.0e38f};
    float lrow[2] = {0.f, 0.f};
    floatx4 oacc[2][4] = {};   // O^T: [mt][dt]; col=l16=q, row=quad*4+r=d-local

    const _Float16* Kbase = Kw + (size_t)bh * SS * DKK;
    const _Float16* Vbase = VTw + (size_t)bh * DKK * SS;

    for (int kt = 0; kt < SS / 64; kt++) {
        const int kb = kt * 64;

        // K A-frags: m=key-local=l16, k=dk
        half8 kf[2][4];
        #pragma unroll
        for (int ks = 0; ks < 2; ks++)
            #pragma unroll
            for (int k2 = 0; k2 < 4; k2++)
                kf[ks][k2] = *(const half8*)(Kbase
                    + (size_t)(kb + k2 * 16 + l16) * DKK + ks * 32 + quad * 8);

        // S^T: D[m=key][n=q]
        floatx4 sacc[2][4] = {};
        #pragma unroll
        for (int mt = 0; mt < 2; mt++)
            #pragma unroll
            for (int ks = 0; ks < 2; ks++)
                #pragma unroll
                for (int k2 = 0; k2 < 4; k2++)
                    sacc[mt][k2] = MFMA16(kf[ks][k2], qf[mt][ks], sacc[mt][k2]);

        // V^T A-frags (issue early; consumed after softmax)
        half8 vf[2][4];
        #pragma unroll
        for (int ks = 0; ks < 2; ks++)
            #pragma unroll
            for (int dt = 0; dt < 4; dt++)
                vf[ks][dt] = *(const half8*)(Vbase
                    + (size_t)(dt * 16 + l16) * SS + kb + ks * 32 + quad * 8);

        // bias for keys kb + k2*16 + quad*4 + r (LDS broadcast across l16)
        float4 bs[4];
        #pragma unroll
        for (int k2 = 0; k2 < 4; k2++)
            bs[k2] = *(const float4*)&Bias[kb + k2 * 16 + quad * 4];

        #pragma unroll
        for (int mt = 0; mt < 2; mt++) {
            float p[4][4];
            #pragma unroll
            for (int k2 = 0; k2 < 4; k2++) {
                const float* bp = (const float*)&bs[k2];
                #pragma unroll
                for (int r = 0; r < 4; r++)
                    p[k2][r] = fmaf(sacc[mt][k2][r], SCL2, bp[r]);
            }
            // row max: 15 in-lane + cross-quad (lanes ^16, ^32)
            float t = p[0][0];
            #pragma unroll
            for (int k2 = 0; k2 < 4; k2++)
                #pragma unroll
                for (int r = 0; r < 4; r++)
                    t = fmaxf(t, p[k2][r]);
            t = fmaxf(t, __shfl_xor(t, 16, 64));
            t = fmaxf(t, __shfl_xor(t, 32, 64));
            float mn = fmaxf(mrow[mt], t);
            float al = exp2f(mrow[mt] - mn);
            mrow[mt] = mn;

            float ps = 0.f;
            #pragma unroll
            for (int k2 = 0; k2 < 4; k2++)
                #pragma unroll
                for (int r = 0; r < 4; r++) {
                    float pv = exp2f(p[k2][r] - mn);
                    p[k2][r] = pv;
                    ps += pv;
                }
            ps += __shfl_xor(ps, 16, 64);
            ps += __shfl_xor(ps, 32, 64);
            lrow[mt] = lrow[mt] * al + ps;

            // packed P store: row q=l16, col key-local
            #pragma unroll
            for (int k2 = 0; k2 < 4; k2++) {
                fp16x2 pa = __builtin_amdgcn_cvt_pkrtz(p[k2][0], p[k2][1]);
                fp16x2 pb = __builtin_amdgcn_cvt_pkrtz(p[k2][2], p[k2][3]);
                *(fp16x2*)&Plds[wave][mt][l16][k2 * 16 + quad * 4]     = pa;
                *(fp16x2*)&Plds[wave][mt][l16][k2 * 16 + quad * 4 + 2] = pb;
            }
            // alpha rescale
            #pragma unroll
            for (int dt = 0; dt < 4; dt++)
                oacc[mt][dt] *= al;

            // PV: O^T += V^T x P^T  (A=vf m=d, B=pf n=q)
            #pragma unroll
            for (int ks = 0; ks < 2; ks++) {
                half8 pf = *(const half8*)&Plds[wave][mt][l16][ks * 32 + quad * 8];
                #pragma unroll
                for (int dt = 0; dt < 4; dt++)
                    oacc[mt][dt] = MFMA16(vf[ks][dt], pf, oacc[mt][dt]);
            }
        }
    }

    // epilogue: float4 loads/stores
    #pragma unroll
    for (int mt = 0; mt < 2; mt++) {
        float rl = 1.0f / lrow[mt];
        int s = qbase + mt * 16 + l16;
        size_t rowoff = ((size_t)b * SS + s) * DMODEL + h * DKK;
        #pragma unroll
        for (int dt = 0; dt < 4; dt++) {
            size_t gi = rowoff + dt * 16 + quad * 4;
            float4 rv = *(const float4*)&resid[gi];
            float4 ov;
            ov.x = oacc[mt][dt][0] * rl + rv.x;
            ov.y = oacc[mt][dt][1] * rl + rv.y;
            ov.z = oacc[mt][dt][2] * rl + rv.z;
            ov.w = oacc[mt][dt][3] * rl + rv.w;
            *(float4*)&out[gi] = ov;
        }
    }
}

// ---------------------------------------------------------------------------
extern "C" void kernel_launch(void* const* d_in, const int* in_sizes, int n_in,
                              void* d_out, int out_size, void* d_ws, size_t ws_size,
                              hipStream_t stream)
{
    const float* q    = (const float*)d_in[0];
    const float* k    = (const float*)d_in[1];
    const float* v    = (const float*)d_in[2];
    const int*   mask = (const int*)d_in[3];
    const float* wq   = (const float*)d_in[4];
    const float* bq   = (const float*)d_in[5];
    const float* wk   = (const float*)d_in[6];
    const float* bk   = (const float*)d_in[7];
    const float* wv   = (const float*)d_in[8];
    const float* bv   = (const float*)d_in[9];
    float* out = (float*)d_out;

    const size_t TENS = (size_t)BB * SS * HH * DKK;   // 8388608 halves
    const size_t WSZ  = (size_t)DMODEL * DMODEL;      // 1048576 halves
    _Float16* base = (_Float16*)d_ws;

    bool big = ws_size >= (6 * TENS + 3 * WSZ) * sizeof(_Float16);
    _Float16 *Xq, *Xk, *Xv, *Qh, *Kh, *VTh, *WTq;
    if (big) {
        Xq = base;            Xk = base + TENS;     Xv = base + 2 * TENS;
        Qh = base + 3 * TENS; Kh = base + 4 * TENS; VTh = base + 5 * TENS;
        WTq = base + 6 * TENS;
    } else {
        // stream-ordered aliasing: Kh reuses Xq's slot, VTh reuses Xk's slot
        Xq = base;            Xk = base + TENS;     Xv = base + 2 * TENS;
        Qh = base + 3 * TENS; Kh = Xq;              VTh = Xk;
        WTq = base + 4 * TENS;
    }
    _Float16* WTk = WTq + WSZ;
    _Float16* WTv = WTk + WSZ;

    if (big) {
        hipLaunchKernelGGL(convert_all, dim3(4096, 4), dim3(256), 0, stream,
                           q, k, v, wq, wk, wv, Xq, Xk, Xv, WTq, WTk, WTv);
        hipLaunchKernelGGL(proj_all, dim3(512, 3), dim3(256), 0, stream,
                           Xq, Xk, Xv, WTq, WTk, WTv, bq, bk, bv, Qh, Kh, VTh);
    } else {
        hipLaunchKernelGGL(convert_x, dim3(4096, 3), dim3(256), 0, stream,
                           q, k, v, Xq, Xk, Xv);
        hipLaunchKernelGGL(convert_wt, dim3(256, 3), dim3(256), 0, stream,
                           wq, wk, wv, WTq, WTk, WTv);
        hipLaunchKernelGGL((proj128<0>), dim3(512), dim3(256), 0, stream, Xq, WTq, bq, Qh);
        hipLaunchKernelGGL((proj128<0>), dim3(512), dim3(256), 0, stream, Xk, WTk, bk, Kh);
        hipLaunchKernelGGL((proj128<1>), dim3(512), dim3(256), 0, stream, Xv, WTv, bv, VTh);
    }
    hipLaunchKernelGGL(flash3, dim3(BB * HH * (SS / 128)), dim3(256), 0, stream,
                       Qh, Kh, VTh, mask, q, out);
}